// Round 13
// baseline (163.231 us; speedup 1.0000x reference)
//
#include <hip/hip_runtime.h>
#include <math.h>

#define HW_N   3136
#define W_DIM  56
#define C_IN   256
#define C_R    32
#define C_OUT  256
#define C_ALL  320
#define K2D    49
#define RS     40        // attn t-row stride in halfs (80 B, 16B-aligned)
#define BN_EPS 1e-5f

typedef _Float16 h2 __attribute__((ext_vector_type(2)));
typedef __fp16  g2 __attribute__((ext_vector_type(2)));   // cvt_pkrtz return type
typedef __fp16  g4 __attribute__((ext_vector_type(4)));
typedef __fp16  g8 __attribute__((ext_vector_type(8)));
typedef float   f4 __attribute__((ext_vector_type(4)));

__device__ __forceinline__ h2 pkrtz(float a, float b) {
    g2 r = __builtin_amdgcn_cvt_pkrtz(a, b);
    return __builtin_bit_cast(h2, r);
}

__device__ __forceinline__ g8 pack8(float4 a, float4 b) {
    g2 p0 = __builtin_amdgcn_cvt_pkrtz(a.x, a.y);
    g2 p1 = __builtin_amdgcn_cvt_pkrtz(a.z, a.w);
    g2 p2 = __builtin_amdgcn_cvt_pkrtz(b.x, b.y);
    g2 p3 = __builtin_amdgcn_cvt_pkrtz(b.z, b.w);
    g8 o;
    o[0] = p0[0]; o[1] = p0[1]; o[2] = p1[0]; o[3] = p1[1];
    o[4] = p2[0]; o[5] = p2[1]; o[6] = p3[0]; o[7] = p3[1];
    return o;
}

__device__ __forceinline__ int refl(int v) {
    v = (v < 0) ? -v : v;
    return (v > 55) ? (110 - v) : v;
}

// Wave-local "barrier": tbuf[w]/pk[w] are wave-private; DS pipe is in-order
// per wave, so we only need the compiler fence + lgkmcnt drain.
__device__ __forceinline__ void wave_fence() {
    asm volatile("s_waitcnt lgkmcnt(0)" ::: "memory");
}

// ---------------------------------------------------------------------------
// Kernel 1: fused transpose + MFMA conv1x1 -> xall16[b][pos][320] f16.
// 32-pos x 320-co tile per block, grid (98,1,4). [round-10 proven: ~17us]
// ---------------------------------------------------------------------------
__global__ __launch_bounds__(256) void k_conv_mfma(
    const float* __restrict__ x,
    const float* __restrict__ w1c, const float* __restrict__ w2c,
    const float* __restrict__ w3c,
    const float* __restrict__ b1c, const float* __restrict__ b2c,
    const float* __restrict__ b3c, __fp16* __restrict__ xall16)
{
    __shared__ __align__(16) _Float16 smem[32 * 328];   // staging 16KB / cs 21KB
    const int t = threadIdx.x, w = t >> 6, lane = t & 63;
    const int quad = lane >> 4, l16 = lane & 15;
    const int b = blockIdx.z, pos0 = blockIdx.x * 32;

    // ---- stage x[b][:][pos0..pos0+31] -> smem h8 slots [p][g], XOR-swizzled
    {
        const int p = t & 31;
        const int gb = t >> 5;               // 0..7
        const float* xp = x + (size_t)b * C_IN * HW_N + pos0 + p;
#pragma unroll
        for (int i = 0; i < 4; ++i) {
            const int g = i * 8 + gb;
            const int ci = g * 8;
            float v[8];
#pragma unroll
            for (int j = 0; j < 8; ++j) v[j] = xp[(size_t)(ci + j) * HW_N];
            g8 o;
#pragma unroll
            for (int jj = 0; jj < 4; ++jj) {
                const g2 pr = __builtin_amdgcn_cvt_pkrtz(v[2 * jj], v[2 * jj + 1]);
                o[2 * jj] = pr[0]; o[2 * jj + 1] = pr[1];
            }
            *(g8*)((__fp16*)smem + (size_t)(p * 32 + (g ^ (p & 7))) * 8) = o;
        }
    }
    __syncthreads();

    // weights rows + bias for this wave's 5 co-tiles (co = w*80 + nt*16 + l16)
    const float* wrow[5]; float bias[5];
#pragma unroll
    for (int nt = 0; nt < 5; ++nt) {
        const int co = w * 80 + nt * 16 + l16;
        wrow[nt] = (co < 32) ? (w1c + co * C_IN)
                 : (co < 64) ? (w2c + (co - 32) * C_IN)
                             : (w3c + (co - 64) * C_IN);
        bias[nt] = (co < 32) ? b1c[co] : (co < 64) ? b2c[co - 32] : b3c[co - 64];
    }

    f4 acc[2][5];
#pragma unroll
    for (int mt = 0; mt < 2; ++mt)
#pragma unroll
        for (int nt = 0; nt < 5; ++nt) acc[mt][nt] = (f4){0.f, 0.f, 0.f, 0.f};

    const int xo = l16 & 7;
#pragma unroll
    for (int ks = 0; ks < 8; ++ks) {
        g8 bf[5];
#pragma unroll
        for (int nt = 0; nt < 5; ++nt) {
            const float* wp = wrow[nt] + ks * 32 + quad * 8;
            bf[nt] = pack8(*(const float4*)wp, *(const float4*)(wp + 4));
        }
#pragma unroll
        for (int mt = 0; mt < 2; ++mt) {
            const int row = mt * 16 + l16;
            const g8 af = *(const g8*)((const __fp16*)smem
                          + (size_t)(row * 32 + ((ks * 4 + quad) ^ xo)) * 8);
#pragma unroll
            for (int nt = 0; nt < 5; ++nt)
                acc[mt][nt] = __builtin_amdgcn_mfma_f32_16x16x32_f16(af, bf[nt], acc[mt][nt], 0, 0, 0);
        }
    }
    __syncthreads();   // all A-frag reads done before smem is reused

    // ---- epilogue: C-frags -> smem f16 [32][328], then coalesced h8 stores
#pragma unroll
    for (int mt = 0; mt < 2; ++mt)
#pragma unroll
        for (int nt = 0; nt < 5; ++nt) {
            const int co = w * 80 + nt * 16 + l16;
#pragma unroll
            for (int r = 0; r < 4; ++r) {
                const int row = mt * 16 + quad * 4 + r;
                smem[row * 328 + co] = (_Float16)(acc[mt][nt][r] + bias[nt]);
            }
        }
    __syncthreads();
#pragma unroll
    for (int i = 0; i < 5; ++i) {
        const int idx = i * 256 + t;        // 0..1279 = 32 rows x 40 h8
        const int row = idx / 40, c8 = idx - row * 40;
        const g8 v = *(const g8*)((const __fp16*)smem + row * 328 + c8 * 8);
        *(g8*)(xall16 + ((size_t)b * HW_N + pos0 + row) * C_ALL + c8 * 8) = v;
    }
}

// ---------------------------------------------------------------------------
// Kernel 2: fused attention + output transpose. One wave per pixel,
// 8 waves / 8 pixels per block (512 thr) to amortize dispatch and raise
// steady-state residency; single block barrier before the transpose.
// stage buffer aliased into tbuf rows 49..63 (garbage rows).
// ---------------------------------------------------------------------------
__global__ __launch_bounds__(512) void k_attn(
    const __fp16* __restrict__ xq,
    const float* __restrict__ bn1_g, const float* __restrict__ bn1_b,
    const float* __restrict__ bn1_m, const float* __restrict__ bn1_v,
    const float* __restrict__ cw1,
    const float* __restrict__ bn2_g, const float* __restrict__ bn2_b,
    const float* __restrict__ bn2_m, const float* __restrict__ bn2_v,
    const float* __restrict__ cw2, const float* __restrict__ cw2_b,
    float* __restrict__ out)
{
    __shared__ __align__(16) _Float16 tbuf[8][64 * RS];   // 64 rows (49 valid)
    __shared__ int pk[8][52];
    const int tid = threadIdx.x;
    const int w = tid >> 6, lane = tid & 63;
    const int b = blockIdx.y;
    const int bid  = blockIdx.x;                 // 0..391
    const int posb = (bid & 7) * 49 + (bid >> 3);   // XCD-contiguous spans
    const int pos0 = posb * 8;
    const int pos  = pos0 + w;
    const int y0 = pos / W_DIM, x0 = pos - y0 * W_DIM;
    const __fp16* __restrict__ base16 = xq + (size_t)b * HW_N * C_ALL;
    _Float16* tb = tbuf[w];
    // per-wave output staging aliases tbuf rows 49..63 (written only after
    // the wave's last read of rows <49; wave-private until __syncthreads)
    float* stage_w = (float*)(tb + 49 * RS);

    // ---- phase 1: t[k][c] = relu(bn1(x1[c] - x2[pk(k)][c])), f16-packed
    {
        const int c2 = lane & 15;        // channel pair
        const int kh = lane >> 4;        // k mod 4 group
        const float2 g = *(const float2*)(bn1_g + 2 * c2);
        const float2 bb = *(const float2*)(bn1_b + 2 * c2);
        const float2 m = *(const float2*)(bn1_m + 2 * c2);
        const float2 v = *(const float2*)(bn1_v + 2 * c2);
        const float iv0 = g.x * rsqrtf(v.x + BN_EPS), bt0 = bb.x - m.x * iv0;
        const float iv1 = g.y * rsqrtf(v.y + BN_EPS), bt1 = bb.y - m.y * iv1;
        const g2 x1p = *(const g2*)(base16 + (size_t)pos * C_ALL + 2 * c2);
        const float x1a = (float)x1p[0], x1b = (float)x1p[1];
#pragma unroll
        for (int j = 0; j < 13; ++j) {
            const int k = 4 * j + kh;
            if (k < K2D) {
                const int dy = k / 7, dx = k - dy * 7;
                const int rp = refl(y0 + dy - 3) * W_DIM + refl(x0 + dx - 3);
                if (c2 == 0) pk[w][k] = rp;
                const g2 x2p = *(const g2*)(base16 + (size_t)rp * C_ALL + 32 + 2 * c2);
                const float t0 = fmaxf((x1a - (float)x2p[0]) * iv0 + bt0, 0.f);
                const float t1 = fmaxf((x1b - (float)x2p[1]) * iv1 + bt1, 0.f);
                *(h2*)&tb[k * RS + 2 * c2] = pkrtz(t0, t1);
            }
        }
    }
    wave_fence();

    const int quad = lane >> 4, l16 = lane & 15;
    f4 acc[4][2];

    // ---- phase 2 (GEMM1): Y1[k][o] = sum_c t[k][c] * cw1[o][c]
    {
        g8 bf[2];
#pragma unroll
        for (int nt = 0; nt < 2; ++nt) {
            const float* wr = cw1 + (nt * 16 + l16) * C_R + quad * 8;
            bf[nt] = pack8(*(const float4*)wr, *(const float4*)(wr + 4));
        }
#pragma unroll
        for (int mt = 0; mt < 4; ++mt) {
            acc[mt][0] = (f4){0.f, 0.f, 0.f, 0.f};
            acc[mt][1] = (f4){0.f, 0.f, 0.f, 0.f};
            const g8 af = *(const g8*)((const __fp16*)tb + (mt * 16 + l16) * RS + quad * 8);
            acc[mt][0] = __builtin_amdgcn_mfma_f32_16x16x32_f16(af, bf[0], acc[mt][0], 0, 0, 0);
            acc[mt][1] = __builtin_amdgcn_mfma_f32_16x16x32_f16(af, bf[1], acc[mt][1], 0, 0, 0);
        }
    }
    wave_fence();

    // ---- BN2 + ReLU on C-frags (col = output channel o), write y2[k][o]
#pragma unroll
    for (int nt = 0; nt < 2; ++nt) {
        const int o = nt * 16 + l16;
        const float iv = bn2_g[o] * rsqrtf(bn2_v[o] + BN_EPS);
        const float bt = bn2_b[o] - bn2_m[o] * iv;
#pragma unroll
        for (int mt = 0; mt < 4; ++mt)
#pragma unroll
            for (int r = 0; r < 4; ++r) {
                const int row = mt * 16 + quad * 4 + r;
                tb[row * RS + o] = (_Float16)fmaxf(acc[mt][nt][r] * iv + bt, 0.f);
            }
    }
    wave_fence();

    // ---- phase 3 (GEMM2): logits[k][h] = cw2_b[h] + sum_o y2[k][o] * cw2[h][o]
    {
        g8 bf[2];
#pragma unroll
        for (int nt = 0; nt < 2; ++nt) {
            const float* wr = cw2 + (nt * 16 + l16) * C_R + quad * 8;
            bf[nt] = pack8(*(const float4*)wr, *(const float4*)(wr + 4));
        }
#pragma unroll
        for (int mt = 0; mt < 4; ++mt) {
            acc[mt][0] = (f4){0.f, 0.f, 0.f, 0.f};
            acc[mt][1] = (f4){0.f, 0.f, 0.f, 0.f};
            const g8 af = *(const g8*)((const __fp16*)tb + (mt * 16 + l16) * RS + quad * 8);
            acc[mt][0] = __builtin_amdgcn_mfma_f32_16x16x32_f16(af, bf[0], acc[mt][0], 0, 0, 0);
            acc[mt][1] = __builtin_amdgcn_mfma_f32_16x16x32_f16(af, bf[1], acc[mt][1], 0, 0, 0);
        }
    }
    wave_fence();

    // ---- phase 4: softmax over k per head h = nt*16+l16; k = mt*16+quad*4+r
    // wgt writes limited to rows < 49 (stage alias lives in rows 49..63).
#pragma unroll
    for (int nt = 0; nt < 2; ++nt) {
        const float bsv = cw2_b[nt * 16 + l16];
        float m = -1e30f;
#pragma unroll
        for (int mt = 0; mt < 4; ++mt)
#pragma unroll
            for (int r = 0; r < 4; ++r) {
                const int k = mt * 16 + quad * 4 + r;
                const float v = acc[mt][nt][r] + bsv;
                acc[mt][nt][r] = v;
                if (k < K2D) m = fmaxf(m, v);
            }
        m = fmaxf(m, __shfl_xor(m, 16, 64));
        m = fmaxf(m, __shfl_xor(m, 32, 64));
        float s = 0.f;
#pragma unroll
        for (int mt = 0; mt < 4; ++mt)
#pragma unroll
            for (int r = 0; r < 4; ++r) {
                const int k = mt * 16 + quad * 4 + r;
                const float e = (k < K2D) ? __expf(acc[mt][nt][r] - m) : 0.f;
                acc[mt][nt][r] = e;
                s += e;
            }
        s += __shfl_xor(s, 16, 64);
        s += __shfl_xor(s, 32, 64);
        const float rs = 1.f / s;
        const int o = nt * 16 + l16;
#pragma unroll
        for (int mt = 0; mt < 4; ++mt)
#pragma unroll
            for (int r = 0; r < 4; ++r) {
                const int row = mt * 16 + quad * 4 + r;
                if (row < K2D)
                    tb[row * RS + o] = (_Float16)(acc[mt][nt][r] * rs);
            }
    }
    wave_fence();

    // ---- phase 5: out[c] = sum_k x3[pk[k]][c] * wgt[k][c>>3]; c = 4*lane..+3
    {
        const int hn = lane >> 1;     // (4*lane)/8
        float4 a = make_float4(0.f, 0.f, 0.f, 0.f);
#pragma unroll 7
        for (int k = 0; k < K2D; ++k) {
            const int rp = pk[w][k];
            const float wv = (float)tb[k * RS + hn];
            const g4 v = *(const g4*)(base16 + (size_t)rp * C_ALL + 64 + lane * 4);
            a.x += (float)v[0] * wv; a.y += (float)v[1] * wv;
            a.z += (float)v[2] * wv; a.w += (float)v[3] * wv;
        }
        *(float4*)&stage_w[lane * 4] = a;
    }
    __syncthreads();

    // ---- transpose through LDS: store out[b][c][pos0+half*4 .. +3]
    {
        const int c    = tid & 255;
        const int half = tid >> 8;           // 0 -> waves 0..3, 1 -> waves 4..7
        const float* st0 = (const float*)(tbuf[half * 4 + 0] + 49 * RS);
        const float* st1 = (const float*)(tbuf[half * 4 + 1] + 49 * RS);
        const float* st2 = (const float*)(tbuf[half * 4 + 2] + 49 * RS);
        const float* st3 = (const float*)(tbuf[half * 4 + 3] + 49 * RS);
        float4 o;
        o.x = st0[c]; o.y = st1[c];
        o.z = st2[c]; o.w = st3[c];
        *(float4*)(out + ((size_t)b * C_OUT + c) * HW_N + pos0 + half * 4) = o;
    }
}

// ---------------------------------------------------------------------------
extern "C" void kernel_launch(void* const* d_in, const int* in_sizes, int n_in,
                              void* d_out, int out_size, void* d_ws, size_t ws_size,
                              hipStream_t stream)
{
    const float* x     = (const float*)d_in[0];
    const float* w1c   = (const float*)d_in[1];
    const float* b1c   = (const float*)d_in[2];
    const float* w2c   = (const float*)d_in[3];
    const float* b2c   = (const float*)d_in[4];
    const float* w3c   = (const float*)d_in[5];
    const float* b3c   = (const float*)d_in[6];
    const float* bn1_g = (const float*)d_in[7];
    const float* bn1_b = (const float*)d_in[8];
    const float* bn1_m = (const float*)d_in[9];
    const float* bn1_v = (const float*)d_in[10];
    const float* cw1   = (const float*)d_in[11];
    const float* bn2_g = (const float*)d_in[12];
    const float* bn2_b = (const float*)d_in[13];
    const float* bn2_m = (const float*)d_in[14];
    const float* bn2_v = (const float*)d_in[15];
    const float* cw2   = (const float*)d_in[16];
    const float* cw2_b = (const float*)d_in[17];

    __fp16* xall16 = (__fp16*)d_ws;                         // [4][3136][320] f16

    k_conv_mfma<<<dim3(98, 1, 4), 256, 0, stream>>>(x, w1c, w2c, w3c,
                                                    b1c, b2c, b3c, xall16);
    k_attn<<<dim3(392, 4, 1), 512, 0, stream>>>(xall16,
        bn1_g, bn1_b, bn1_m, bn1_v, cw1,
        bn2_g, bn2_b, bn2_m, bn2_v, cw2, cw2_b, (float*)d_out);
}

// Round 14
// 156.466 us; speedup vs baseline: 1.0432x; 1.0432x over previous
//
#include <hip/hip_runtime.h>
#include <math.h>

#define HW_N   3136
#define W_DIM  56
#define C_IN   256
#define C_R    32
#define C_OUT  256
#define C_ALL  320
#define K2D    49
#define RS     40        // attn t-row stride in halfs (80 B, 16B-aligned)
#define BN_EPS 1e-5f

typedef _Float16 h2 __attribute__((ext_vector_type(2)));
typedef _Float16 h4 __attribute__((ext_vector_type(4)));
typedef __fp16  g2 __attribute__((ext_vector_type(2)));   // cvt_pkrtz return type
typedef __fp16  g4 __attribute__((ext_vector_type(4)));
typedef __fp16  g8 __attribute__((ext_vector_type(8)));
typedef float   f4 __attribute__((ext_vector_type(4)));

__device__ __forceinline__ h2 pkrtz(float a, float b) {
    g2 r = __builtin_amdgcn_cvt_pkrtz(a, b);
    return __builtin_bit_cast(h2, r);
}

__device__ __forceinline__ g8 pack8(float4 a, float4 b) {
    g2 p0 = __builtin_amdgcn_cvt_pkrtz(a.x, a.y);
    g2 p1 = __builtin_amdgcn_cvt_pkrtz(a.z, a.w);
    g2 p2 = __builtin_amdgcn_cvt_pkrtz(b.x, b.y);
    g2 p3 = __builtin_amdgcn_cvt_pkrtz(b.z, b.w);
    g8 o;
    o[0] = p0[0]; o[1] = p0[1]; o[2] = p1[0]; o[3] = p1[1];
    o[4] = p2[0]; o[5] = p2[1]; o[6] = p3[0]; o[7] = p3[1];
    return o;
}

__device__ __forceinline__ int refl(int v) {
    v = (v < 0) ? -v : v;
    return (v > 55) ? (110 - v) : v;
}

// Wave-local "barrier": tbuf[w]/pk[w] are wave-private; DS pipe is in-order
// per wave, so we only need the compiler fence + lgkmcnt drain.
__device__ __forceinline__ void wave_fence() {
    asm volatile("s_waitcnt lgkmcnt(0)" ::: "memory");
}

// ---------------------------------------------------------------------------
// Kernel 1: fused transpose + MFMA conv1x1 -> xall16[b][pos][320] f16.
// 32-pos x 320-co tile per block, grid (98,1,4). [round-10 proven: ~17us]
// ---------------------------------------------------------------------------
__global__ __launch_bounds__(256) void k_conv_mfma(
    const float* __restrict__ x,
    const float* __restrict__ w1c, const float* __restrict__ w2c,
    const float* __restrict__ w3c,
    const float* __restrict__ b1c, const float* __restrict__ b2c,
    const float* __restrict__ b3c, __fp16* __restrict__ xall16)
{
    __shared__ __align__(16) _Float16 smem[32 * 328];   // staging 16KB / cs 21KB
    const int t = threadIdx.x, w = t >> 6, lane = t & 63;
    const int quad = lane >> 4, l16 = lane & 15;
    const int b = blockIdx.z, pos0 = blockIdx.x * 32;

    // ---- stage x[b][:][pos0..pos0+31] -> smem h8 slots [p][g], XOR-swizzled
    {
        const int p = t & 31;
        const int gb = t >> 5;               // 0..7
        const float* xp = x + (size_t)b * C_IN * HW_N + pos0 + p;
#pragma unroll
        for (int i = 0; i < 4; ++i) {
            const int g = i * 8 + gb;
            const int ci = g * 8;
            float v[8];
#pragma unroll
            for (int j = 0; j < 8; ++j) v[j] = xp[(size_t)(ci + j) * HW_N];
            g8 o;
#pragma unroll
            for (int jj = 0; jj < 4; ++jj) {
                const g2 pr = __builtin_amdgcn_cvt_pkrtz(v[2 * jj], v[2 * jj + 1]);
                o[2 * jj] = pr[0]; o[2 * jj + 1] = pr[1];
            }
            *(g8*)((__fp16*)smem + (size_t)(p * 32 + (g ^ (p & 7))) * 8) = o;
        }
    }
    __syncthreads();

    // weights rows + bias for this wave's 5 co-tiles (co = w*80 + nt*16 + l16)
    const float* wrow[5]; float bias[5];
#pragma unroll
    for (int nt = 0; nt < 5; ++nt) {
        const int co = w * 80 + nt * 16 + l16;
        wrow[nt] = (co < 32) ? (w1c + co * C_IN)
                 : (co < 64) ? (w2c + (co - 32) * C_IN)
                             : (w3c + (co - 64) * C_IN);
        bias[nt] = (co < 32) ? b1c[co] : (co < 64) ? b2c[co - 32] : b3c[co - 64];
    }

    f4 acc[2][5];
#pragma unroll
    for (int mt = 0; mt < 2; ++mt)
#pragma unroll
        for (int nt = 0; nt < 5; ++nt) acc[mt][nt] = (f4){0.f, 0.f, 0.f, 0.f};

    const int xo = l16 & 7;
#pragma unroll
    for (int ks = 0; ks < 8; ++ks) {
        g8 bf[5];
#pragma unroll
        for (int nt = 0; nt < 5; ++nt) {
            const float* wp = wrow[nt] + ks * 32 + quad * 8;
            bf[nt] = pack8(*(const float4*)wp, *(const float4*)(wp + 4));
        }
#pragma unroll
        for (int mt = 0; mt < 2; ++mt) {
            const int row = mt * 16 + l16;
            const g8 af = *(const g8*)((const __fp16*)smem
                          + (size_t)(row * 32 + ((ks * 4 + quad) ^ xo)) * 8);
#pragma unroll
            for (int nt = 0; nt < 5; ++nt)
                acc[mt][nt] = __builtin_amdgcn_mfma_f32_16x16x32_f16(af, bf[nt], acc[mt][nt], 0, 0, 0);
        }
    }
    __syncthreads();   // all A-frag reads done before smem is reused

    // ---- epilogue: C-frags -> smem f16 [32][328], then coalesced h8 stores
#pragma unroll
    for (int mt = 0; mt < 2; ++mt)
#pragma unroll
        for (int nt = 0; nt < 5; ++nt) {
            const int co = w * 80 + nt * 16 + l16;
#pragma unroll
            for (int r = 0; r < 4; ++r) {
                const int row = mt * 16 + quad * 4 + r;
                smem[row * 328 + co] = (_Float16)(acc[mt][nt][r] + bias[nt]);
            }
        }
    __syncthreads();
#pragma unroll
    for (int i = 0; i < 5; ++i) {
        const int idx = i * 256 + t;        // 0..1279 = 32 rows x 40 h8
        const int row = idx / 40, c8 = idx - row * 40;
        const g8 v = *(const g8*)((const __fp16*)smem + row * 328 + c8 * 8);
        *(g8*)(xall16 + ((size_t)b * HW_N + pos0 + row) * C_ALL + c8 * 8) = v;
    }
}

// ---------------------------------------------------------------------------
// Kernel 2: fused attention + output transpose. One wave per pixel,
// 4 waves/block; single block barrier at the very end for the transpose.
// stage buffer aliased into tbuf rows 49..63 (garbage rows) -> LDS 21504 B.
// ---------------------------------------------------------------------------
__global__ __launch_bounds__(256) void k_attn(
    const __fp16* __restrict__ xq,
    const float* __restrict__ bn1_g, const float* __restrict__ bn1_b,
    const float* __restrict__ bn1_m, const float* __restrict__ bn1_v,
    const float* __restrict__ cw1,
    const float* __restrict__ bn2_g, const float* __restrict__ bn2_b,
    const float* __restrict__ bn2_m, const float* __restrict__ bn2_v,
    const float* __restrict__ cw2, const float* __restrict__ cw2_b,
    float* __restrict__ out)
{
    __shared__ __align__(16) _Float16 tbuf[4][64 * RS];   // 64 rows (49 valid)
    __shared__ int pk[4][52];
    const int tid = threadIdx.x;
    const int w = tid >> 6, lane = tid & 63;
    const int b = blockIdx.y;
    const int bid  = blockIdx.x;                 // 0..783
    const int posb = (bid & 7) * 98 + (bid >> 3);   // XCD-contiguous spans
    const int pos0 = posb * 4;
    const int pos  = pos0 + w;
    const int y0 = pos / W_DIM, x0 = pos - y0 * W_DIM;
    const __fp16* __restrict__ base16 = xq + (size_t)b * HW_N * C_ALL;
    _Float16* tb = tbuf[w];
    // per-wave output staging aliases tbuf rows 49..63 (written only after
    // the wave's last read of rows <49; wave-private until __syncthreads)
    float* stage_w = (float*)(tb + 49 * RS);

    // ---- phase 1: t[k][c] = relu(bn1(x1[c] - x2[pk(k)][c])), f16-packed.
    // lane = kh*8 + c4: channel-QUAD per lane (g4 loads, 7 passes of 8 rows)
    // -- halves scattered-load and DS-write issue count vs 13x g2.
    {
        const int c4 = lane & 7;         // channel quad (4 ch)
        const int kh = lane >> 3;        // k mod 8 group
        const float4 g  = *(const float4*)(bn1_g + 4 * c4);
        const float4 bb = *(const float4*)(bn1_b + 4 * c4);
        const float4 m  = *(const float4*)(bn1_m + 4 * c4);
        const float4 v  = *(const float4*)(bn1_v + 4 * c4);
        const float iv0 = g.x * rsqrtf(v.x + BN_EPS), bt0 = bb.x - m.x * iv0;
        const float iv1 = g.y * rsqrtf(v.y + BN_EPS), bt1 = bb.y - m.y * iv1;
        const float iv2 = g.z * rsqrtf(v.z + BN_EPS), bt2 = bb.z - m.z * iv2;
        const float iv3 = g.w * rsqrtf(v.w + BN_EPS), bt3 = bb.w - m.w * iv3;
        const g4 x1p = *(const g4*)(base16 + (size_t)pos * C_ALL + 4 * c4);
        const float x1a = (float)x1p[0], x1b = (float)x1p[1];
        const float x1c = (float)x1p[2], x1d = (float)x1p[3];
#pragma unroll
        for (int j = 0; j < 7; ++j) {
            const int k = 8 * j + kh;
            if (k < K2D) {
                const int dy = k / 7, dx = k - dy * 7;
                const int rp = refl(y0 + dy - 3) * W_DIM + refl(x0 + dx - 3);
                if (c4 == 0) pk[w][k] = rp;
                const g4 x2p = *(const g4*)(base16 + (size_t)rp * C_ALL + 32 + 4 * c4);
                const float t0 = fmaxf((x1a - (float)x2p[0]) * iv0 + bt0, 0.f);
                const float t1 = fmaxf((x1b - (float)x2p[1]) * iv1 + bt1, 0.f);
                const float t2 = fmaxf((x1c - (float)x2p[2]) * iv2 + bt2, 0.f);
                const float t3 = fmaxf((x1d - (float)x2p[3]) * iv3 + bt3, 0.f);
                const h2 lo = pkrtz(t0, t1), hi = pkrtz(t2, t3);
                h4 tt; tt[0] = lo[0]; tt[1] = lo[1]; tt[2] = hi[0]; tt[3] = hi[1];
                *(h4*)&tb[k * RS + 4 * c4] = tt;
            }
        }
    }
    wave_fence();

    const int quad = lane >> 4, l16 = lane & 15;
    f4 acc[4][2];

    // ---- phase 2 (GEMM1): Y1[k][o] = sum_c t[k][c] * cw1[o][c]
    {
        g8 bf[2];
#pragma unroll
        for (int nt = 0; nt < 2; ++nt) {
            const float* wr = cw1 + (nt * 16 + l16) * C_R + quad * 8;
            bf[nt] = pack8(*(const float4*)wr, *(const float4*)(wr + 4));
        }
#pragma unroll
        for (int mt = 0; mt < 4; ++mt) {
            acc[mt][0] = (f4){0.f, 0.f, 0.f, 0.f};
            acc[mt][1] = (f4){0.f, 0.f, 0.f, 0.f};
            const g8 af = *(const g8*)((const __fp16*)tb + (mt * 16 + l16) * RS + quad * 8);
            acc[mt][0] = __builtin_amdgcn_mfma_f32_16x16x32_f16(af, bf[0], acc[mt][0], 0, 0, 0);
            acc[mt][1] = __builtin_amdgcn_mfma_f32_16x16x32_f16(af, bf[1], acc[mt][1], 0, 0, 0);
        }
    }
    wave_fence();

    // ---- BN2 + ReLU on C-frags (col = output channel o), write y2[k][o]
#pragma unroll
    for (int nt = 0; nt < 2; ++nt) {
        const int o = nt * 16 + l16;
        const float iv = bn2_g[o] * rsqrtf(bn2_v[o] + BN_EPS);
        const float bt = bn2_b[o] - bn2_m[o] * iv;
#pragma unroll
        for (int mt = 0; mt < 4; ++mt)
#pragma unroll
            for (int r = 0; r < 4; ++r) {
                const int row = mt * 16 + quad * 4 + r;
                tb[row * RS + o] = (_Float16)fmaxf(acc[mt][nt][r] * iv + bt, 0.f);
            }
    }
    wave_fence();

    // ---- phase 3 (GEMM2): logits[k][h] = cw2_b[h] + sum_o y2[k][o] * cw2[h][o]
    {
        g8 bf[2];
#pragma unroll
        for (int nt = 0; nt < 2; ++nt) {
            const float* wr = cw2 + (nt * 16 + l16) * C_R + quad * 8;
            bf[nt] = pack8(*(const float4*)wr, *(const float4*)(wr + 4));
        }
#pragma unroll
        for (int mt = 0; mt < 4; ++mt) {
            acc[mt][0] = (f4){0.f, 0.f, 0.f, 0.f};
            acc[mt][1] = (f4){0.f, 0.f, 0.f, 0.f};
            const g8 af = *(const g8*)((const __fp16*)tb + (mt * 16 + l16) * RS + quad * 8);
            acc[mt][0] = __builtin_amdgcn_mfma_f32_16x16x32_f16(af, bf[0], acc[mt][0], 0, 0, 0);
            acc[mt][1] = __builtin_amdgcn_mfma_f32_16x16x32_f16(af, bf[1], acc[mt][1], 0, 0, 0);
        }
    }
    wave_fence();

    // ---- phase 4: softmax over k per head h = nt*16+l16; k = mt*16+quad*4+r
    // wgt writes limited to rows < 49 (stage alias lives in rows 49..63).
#pragma unroll
    for (int nt = 0; nt < 2; ++nt) {
        const float bsv = cw2_b[nt * 16 + l16];
        float m = -1e30f;
#pragma unroll
        for (int mt = 0; mt < 4; ++mt)
#pragma unroll
            for (int r = 0; r < 4; ++r) {
                const int k = mt * 16 + quad * 4 + r;
                const float v = acc[mt][nt][r] + bsv;
                acc[mt][nt][r] = v;
                if (k < K2D) m = fmaxf(m, v);
            }
        m = fmaxf(m, __shfl_xor(m, 16, 64));
        m = fmaxf(m, __shfl_xor(m, 32, 64));
        float s = 0.f;
#pragma unroll
        for (int mt = 0; mt < 4; ++mt)
#pragma unroll
            for (int r = 0; r < 4; ++r) {
                const int k = mt * 16 + quad * 4 + r;
                const float e = (k < K2D) ? __expf(acc[mt][nt][r] - m) : 0.f;
                acc[mt][nt][r] = e;
                s += e;
            }
        s += __shfl_xor(s, 16, 64);
        s += __shfl_xor(s, 32, 64);
        const float rs = 1.f / s;
        const int o = nt * 16 + l16;
#pragma unroll
        for (int mt = 0; mt < 4; ++mt)
#pragma unroll
            for (int r = 0; r < 4; ++r) {
                const int row = mt * 16 + quad * 4 + r;
                if (row < K2D)
                    tb[row * RS + o] = (_Float16)(acc[mt][nt][r] * rs);
            }
    }
    wave_fence();

    // ---- phase 5: out[c] = sum_k x3[pk[k]][c] * wgt[k][c>>3]; c = 4*lane..+3
    {
        const int hn = lane >> 1;     // (4*lane)/8
        float4 a = make_float4(0.f, 0.f, 0.f, 0.f);
#pragma unroll 7
        for (int k = 0; k < K2D; ++k) {
            const int rp = pk[w][k];
            const float wv = (float)tb[k * RS + hn];
            const g4 v = *(const g4*)(base16 + (size_t)rp * C_ALL + 64 + lane * 4);
            a.x += (float)v[0] * wv; a.y += (float)v[1] * wv;
            a.z += (float)v[2] * wv; a.w += (float)v[3] * wv;
        }
        *(float4*)&stage_w[lane * 4] = a;
    }
    __syncthreads();

    // ---- transpose through LDS: store out[b][c][pos0..pos0+3]
    {
        const int c = tid;
        const float* st0 = (const float*)(tbuf[0] + 49 * RS);
        const float* st1 = (const float*)(tbuf[1] + 49 * RS);
        const float* st2 = (const float*)(tbuf[2] + 49 * RS);
        const float* st3 = (const float*)(tbuf[3] + 49 * RS);
        float4 o;
        o.x = st0[c]; o.y = st1[c];
        o.z = st2[c]; o.w = st3[c];
        *(float4*)(out + ((size_t)b * C_OUT + c) * HW_N + pos0) = o;
    }
}

// ---------------------------------------------------------------------------
extern "C" void kernel_launch(void* const* d_in, const int* in_sizes, int n_in,
                              void* d_out, int out_size, void* d_ws, size_t ws_size,
                              hipStream_t stream)
{
    const float* x     = (const float*)d_in[0];
    const float* w1c   = (const float*)d_in[1];
    const float* b1c   = (const float*)d_in[2];
    const float* w2c   = (const float*)d_in[3];
    const float* b2c   = (const float*)d_in[4];
    const float* w3c   = (const float*)d_in[5];
    const float* b3c   = (const float*)d_in[6];
    const float* bn1_g = (const float*)d_in[7];
    const float* bn1_b = (const float*)d_in[8];
    const float* bn1_m = (const float*)d_in[9];
    const float* bn1_v = (const float*)d_in[10];
    const float* cw1   = (const float*)d_in[11];
    const float* bn2_g = (const float*)d_in[12];
    const float* bn2_b = (const float*)d_in[13];
    const float* bn2_m = (const float*)d_in[14];
    const float* bn2_v = (const float*)d_in[15];
    const float* cw2   = (const float*)d_in[16];
    const float* cw2_b = (const float*)d_in[17];

    __fp16* xall16 = (__fp16*)d_ws;                         // [4][3136][320] f16

    k_conv_mfma<<<dim3(98, 1, 4), 256, 0, stream>>>(x, w1c, w2c, w3c,
                                                    b1c, b2c, b3c, xall16);
    k_attn<<<dim3(784, 4, 1), 256, 0, stream>>>(xall16,
        bn1_g, bn1_b, bn1_m, bn1_v, cw1,
        bn2_g, bn2_b, bn2_m, bn2_v, cw2, cw2_b, (float*)d_out);
}